// Round 12
// baseline (150.227 us; speedup 1.0000x reference)
//
#include <hip/hip_runtime.h>
#include <math.h>

// Problem constants (from reference setup_inputs)
#define BQ 778          // points per cloud
#define NF_IN 1538      // input faces
#define NF_NEW 14       // appended constant faces
#define NT 1552         // total triangles (= 16 waves * 97)
#define NB 8            // batch
#define BLOCK 1024
#define NWAVE 16
#define TRI_PER_WAVE 97 // 16*97 = 1552 exactly

__constant__ int FACES_NEW_D[NF_NEW * 3] = {
    92, 38, 234, 234, 38, 239, 38, 122, 239, 239, 122, 279,
    122, 118, 279, 279, 118, 215, 118, 117, 215, 215, 117, 214,
    117, 119, 214, 214, 119, 121, 119, 120, 121, 121, 120, 78,
    120, 108, 78, 78, 108, 79};

// Fast atan2 (~25 VALU ops): min/max range reduction, rcp+Newton divide,
// SLEEF degree-19 odd minimax on [0,1], quadrant fixup, copysign keeps
// +/-0 and +/-pi semantics. Validated round 10: absmax 0.0 vs reference
// (atan2 only feeds the wn>=0.99 classification, which has slack).
__device__ __forceinline__ float fast_atan2f(float y, float x) {
  float ax = __builtin_fabsf(x), ay = __builtin_fabsf(y);
  float mx = fmaxf(ax, ay), mn = fminf(ax, ay);
  float r  = __builtin_amdgcn_rcpf(mx);
  float t  = mn * r;
  float e  = __builtin_fmaf(-t, mx, mn);
  t = __builtin_fmaf(e, r, t);
  float s = t * t;
  float u =                  0.00282363896258175373077393f;
  u = __builtin_fmaf(u, s, -0.0159569028764963150024414f);
  u = __builtin_fmaf(u, s,  0.0425049886107444763183594f);
  u = __builtin_fmaf(u, s, -0.0748900920152664184570312f);
  u = __builtin_fmaf(u, s,  0.106347933411598205566406f);
  u = __builtin_fmaf(u, s, -0.142027363181114196777344f);
  u = __builtin_fmaf(u, s,  0.199926957488059997558594f);
  u = __builtin_fmaf(u, s, -0.333331018686294555664062f);
  float a = __builtin_fmaf(u * s, t, t);
  a = (ay > ax) ? (1.57079632679489662f - a) : a;
  a = (x < 0.0f) ? (3.14159265358979323f - a) : a;
  return __builtin_copysignf(a, y);
}

// TRANSPOSED layout: lane = query point, loop = triangles.
// Every lane in a wave reads the SAME triangle per iteration -> all LDS
// reads are uniform-address broadcasts (bank-conflict-free by definition).
// Block = (cloud, point-group of 64). 16 waves; wave w owns triangles
// [w*97, (w+1)*97) and strided slice of the dist loop. Per-wave partials
// are combined by wave 0 in a fixed order (deterministic).
__global__ __launch_bounds__(BLOCK) void wn_dist_kernel(
    const float* __restrict__ v1, const float* __restrict__ v2,
    const int* __restrict__ faces, float* __restrict__ sums,
    unsigned int* __restrict__ flags) {
  __shared__ float4 sv[BQ];       // 12448 B vertex cloud (w unused)
  __shared__ ushort4 sf4[NT];     // 12416 B byte offsets (idx*16)
  __shared__ float romega[NWAVE][64];  // 4096 B
  __shared__ float rdmin[NWAVE][64];   // 4096 B

  const int PG = 13;              // point-groups per cloud (13*64 >= 778)
  int bid = blockIdx.x;
  int cloud = bid / PG;           // 0..15
  int pg = bid % PG;
  int side = cloud >> 3;
  int b = cloud & 7;

  const float* pts = (side == 0) ? (v1 + b * BQ * 3) : (v2 + b * BQ * 3);
  const float* opp = (side == 0) ? (v2 + b * BQ * 3) : (v1 + b * BQ * 3);

  int tid = threadIdx.x;
  for (int i = tid; i < BQ; i += BLOCK) {
    sv[i] = make_float4(opp[i * 3 + 0], opp[i * 3 + 1], opp[i * 3 + 2], 0.0f);
  }
  for (int f = tid; f < NF_IN; f += BLOCK) {
    ushort4 u;
    u.x = (unsigned short)(faces[f * 3 + 0] << 4);
    u.y = (unsigned short)(faces[f * 3 + 1] << 4);
    u.z = (unsigned short)(faces[f * 3 + 2] << 4);
    u.w = 0;
    sf4[f] = u;
  }
  for (int f = tid; f < NF_NEW; f += BLOCK) {
    ushort4 u;
    u.x = (unsigned short)(FACES_NEW_D[f * 3 + 0] << 4);
    u.y = (unsigned short)(FACES_NEW_D[f * 3 + 1] << 4);
    u.z = (unsigned short)(FACES_NEW_D[f * 3 + 2] << 4);
    u.w = 0;
    sf4[NF_IN + f] = u;
  }
  __syncthreads();

  int wave = tid >> 6;
  int lane = tid & 63;
  int q = pg * 64 + lane;          // this lane's query point
  bool valid = (q < BQ);
  int qc = valid ? q : (BQ - 1);   // clamp for loads only

  const float sgn = side ? -1.0f : 1.0f;
  float px = pts[qc * 3 + 0];
  float py = pts[qc * 3 + 1];
  float pz = pts[qc * 3 + 2];

  const char* svb = (const char*)sv;

  // ---- winding partial: this wave's 97 triangles, lanes = 64 points ----
  float omega = 0.0f;
  int tbase = wave * TRI_PER_WAVE;
  for (int k = 0; k < TRI_PER_WAVE; ++k) {
    ushort4 f = sf4[tbase + k];    // uniform in wave -> broadcast
    float4 va = *(const float4*)(svb + f.x);   // broadcast
    float4 vb = *(const float4*)(svb + f.y);   // broadcast
    float4 vc = *(const float4*)(svb + f.z);   // broadcast
    float ax = va.x - px, ay = va.y - py, az = va.z - pz;
    float bx = vb.x - px, by = vb.y - py, bz = vb.z - pz;
    float cx = vc.x - px, cy = vc.y - py, cz = vc.z - pz;
    float la = sqrtf(ax * ax + ay * ay + az * az);
    float lb = sqrtf(bx * bx + by * by + bz * bz);
    float lc = sqrtf(cx * cx + cy * cy + cz * cz);
    float crx = by * cz - bz * cy;
    float cry = bz * cx - bx * cz;
    float crz = bx * cy - by * cx;
    float num = ax * crx + ay * cry + az * crz;
    float d01 = ax * bx + ay * by + az * bz;
    float d02 = ax * cx + ay * cy + az * cz;
    float d12 = bx * cx + by * cy + bz * cz;
    float den = la * lb * lc + d01 * lc + d02 * lb + d12 * la;
    omega += fast_atan2f(sgn * num, den);
  }

  // ---- dist partial: strided slice of opposite cloud, uniform j ----
  float dmin = 3.402823466e38f;
  for (int j = wave; j < BQ; j += NWAVE) {
    float4 vj = sv[j];             // uniform in wave -> broadcast
    float dx = vj.x - px, dy = vj.y - py, dz = vj.z - pz;
    dmin = fminf(dmin, dx * dx + dy * dy + dz * dz);
  }

  romega[wave][lane] = omega;
  rdmin[wave][lane] = dmin;
  __syncthreads();

  // ---- wave 0: fixed-order combine (deterministic), then accumulate ----
  if (wave == 0) {
    float om = 0.0f;
    float dm = 3.402823466e38f;
#pragma unroll
    for (int w = 0; w < NWAVE; ++w) {
      om += romega[w][lane];       // stride-1 across lanes, conflict-free
      dm = fminf(dm, rdmin[w][lane]);
    }
    float wn = om * 0.15915494309189535f;  // sum(atan2)/(2*pi)
    bool interior = valid && (wn >= 0.99f);
    float pt = interior ? fmaxf(dm, 0.0f) * 10000.0f : 0.0f;
    for (int off = 32; off; off >>= 1) pt += __shfl_xor(pt, off);
    bool anyint = __any(interior);
    if (lane == 0) {
      atomicAdd(&sums[cloud], pt);
      if (anyint) atomicOr(&flags[cloud], 1u);
    }
  }
}

__global__ void finalize_kernel(const float* __restrict__ sums,
                                const unsigned int* __restrict__ flags,
                                float* __restrict__ out) {
  if (threadIdx.x == 0) {
    float total = 0.0f;
    for (int b = 0; b < NB; ++b) {
      bool gate = (flags[b] != 0u) && (flags[NB + b] != 0u);
      if (gate) total += sums[b] + sums[NB + b];
    }
    out[0] = total * (1.0f / NB);
  }
}

extern "C" void kernel_launch(void* const* d_in, const int* in_sizes, int n_in,
                              void* d_out, int out_size, void* d_ws,
                              size_t ws_size, hipStream_t stream) {
  const float* v1 = (const float*)d_in[0];
  const float* v2 = (const float*)d_in[1];
  const int* faces = (const int*)d_in[2];
  float* out = (float*)d_out;

  float* sums = (float*)d_ws;                       // 16 floats
  unsigned int* flags = (unsigned int*)(sums + 16); // 16 uints

  hipMemsetAsync(d_ws, 0, 16 * sizeof(float) + 16 * sizeof(unsigned int),
                 stream);

  int grid = 16 * 13;  // clouds x point-groups = 208 blocks of 1024
  wn_dist_kernel<<<grid, BLOCK, 0, stream>>>(v1, v2, faces, sums, flags);
  finalize_kernel<<<1, 64, 0, stream>>>(sums, flags, out);
}

// Round 13
// 122.649 us; speedup vs baseline: 1.2248x; 1.2248x over previous
//
#include <hip/hip_runtime.h>
#include <math.h>

// Problem constants (from reference setup_inputs)
#define BQ 778          // points per cloud
#define NF_IN 1538      // input faces
#define NF_NEW 14       // appended constant faces
#define NT 1552         // total triangles
#define NB 8            // batch
#define BLOCK 512
#define NWAVE 8         // waves per block
#define NSPLIT 4        // blocks per (cloud, point-group): triangle split
#define NSLOT 32        // NWAVE*NSPLIT wave-slots covering NT and dist-j
#define PG 13           // point-groups of 64 per cloud (13*64 >= 778)

__constant__ int FACES_NEW_D[NF_NEW * 3] = {
    92, 38, 234, 234, 38, 239, 38, 122, 239, 239, 122, 279,
    122, 118, 279, 279, 118, 215, 118, 117, 215, 215, 117, 214,
    117, 119, 214, 214, 119, 121, 119, 120, 121, 121, 120, 78,
    120, 108, 78, 78, 108, 79};

// Fast atan2 (~25 VALU): validated rounds 10/12 (absmax 0.0).
__device__ __forceinline__ float fast_atan2f(float y, float x) {
  float ax = __builtin_fabsf(x), ay = __builtin_fabsf(y);
  float mx = fmaxf(ax, ay), mn = fminf(ax, ay);
  float r  = __builtin_amdgcn_rcpf(mx);
  float t  = mn * r;
  float e  = __builtin_fmaf(-t, mx, mn);
  t = __builtin_fmaf(e, r, t);
  float s = t * t;
  float u =                  0.00282363896258175373077393f;
  u = __builtin_fmaf(u, s, -0.0159569028764963150024414f);
  u = __builtin_fmaf(u, s,  0.0425049886107444763183594f);
  u = __builtin_fmaf(u, s, -0.0748900920152664184570312f);
  u = __builtin_fmaf(u, s,  0.106347933411598205566406f);
  u = __builtin_fmaf(u, s, -0.142027363181114196777344f);
  u = __builtin_fmaf(u, s,  0.199926957488059997558594f);
  u = __builtin_fmaf(u, s, -0.333331018686294555664062f);
  float a = __builtin_fmaf(u * s, t, t);
  a = (ay > ax) ? (1.57079632679489662f - a) : a;
  a = (x < 0.0f) ? (3.14159265358979323f - a) : a;
  return __builtin_copysignf(a, y);
}

// Kernel 1: transposed broadcast layout (lane = point, loop = triangles;
// all LDS reads wave-uniform -> conflict-free, confirmed R12: conflicts=0).
// R12 was latency-bound: 208 blocks (<256 CUs!), 97-deep serial chains.
// Fix: NSPLIT=4 triangle split -> 832 blocks, ~26 resident waves/CU,
// ~49 iters/wave. Partials stored per (split,cloud,point); NO atomics ->
// fully deterministic (block combines its 8 waves in fixed order; kernel2
// combines the 4 splits in fixed order).
__global__ __launch_bounds__(BLOCK) void wn_part_kernel(
    const float* __restrict__ v1, const float* __restrict__ v2,
    const int* __restrict__ faces,
    float* __restrict__ omega_part, float* __restrict__ dmin_part) {
  __shared__ float4 sv[BQ];        // 12448 B
  __shared__ ushort4 sf4[NT];      // 12416 B (byte offsets, idx*16)
  __shared__ float romega[NWAVE][64];  // 2048 B
  __shared__ float rdmin[NWAVE][64];   // 2048 B

  int bid = blockIdx.x;
  int split = bid & (NSPLIT - 1);
  int rest = bid >> 2;
  int pg = rest % PG;
  int cloud = rest / PG;           // 0..15
  int side = cloud >> 3;
  int b = cloud & 7;

  const float* pts = (side == 0) ? (v1 + b * BQ * 3) : (v2 + b * BQ * 3);
  const float* opp = (side == 0) ? (v2 + b * BQ * 3) : (v1 + b * BQ * 3);

  int tid = threadIdx.x;
  for (int i = tid; i < BQ; i += BLOCK) {
    sv[i] = make_float4(opp[i * 3 + 0], opp[i * 3 + 1], opp[i * 3 + 2], 0.0f);
  }
  for (int f = tid; f < NF_IN; f += BLOCK) {
    ushort4 u;
    u.x = (unsigned short)(faces[f * 3 + 0] << 4);
    u.y = (unsigned short)(faces[f * 3 + 1] << 4);
    u.z = (unsigned short)(faces[f * 3 + 2] << 4);
    u.w = 0;
    sf4[f] = u;
  }
  for (int f = tid; f < NF_NEW; f += BLOCK) {
    ushort4 u;
    u.x = (unsigned short)(FACES_NEW_D[f * 3 + 0] << 4);
    u.y = (unsigned short)(FACES_NEW_D[f * 3 + 1] << 4);
    u.z = (unsigned short)(FACES_NEW_D[f * 3 + 2] << 4);
    u.w = 0;
    sf4[NF_IN + f] = u;
  }
  __syncthreads();

  int wave = tid >> 6;
  int lane = tid & 63;
  int q = pg * 64 + lane;
  bool valid = (q < BQ);
  int qc = valid ? q : (BQ - 1);

  const float sgn = side ? -1.0f : 1.0f;
  float px = pts[qc * 3 + 0];
  float py = pts[qc * 3 + 1];
  float pz = pts[qc * 3 + 2];

  const char* svb = (const char*)sv;

  // This wave-slot's triangle range: slots 0..15 take 49, 16..31 take 48.
  int slot = split * NWAVE + wave;  // 0..31
  int tstart = slot * 48 + (slot < 16 ? slot : 16);
  int tcount = (slot < 16) ? 49 : 48;

  float omega = 0.0f;
#pragma unroll 2
  for (int k = 0; k < tcount; ++k) {
    ushort4 f = sf4[tstart + k];    // uniform -> broadcast
    float4 va = *(const float4*)(svb + f.x);
    float4 vb = *(const float4*)(svb + f.y);
    float4 vc = *(const float4*)(svb + f.z);
    float ax = va.x - px, ay = va.y - py, az = va.z - pz;
    float bx = vb.x - px, by = vb.y - py, bz = vb.z - pz;
    float cx = vc.x - px, cy = vc.y - py, cz = vc.z - pz;
    float la = __builtin_amdgcn_sqrtf(ax * ax + ay * ay + az * az);
    float lb = __builtin_amdgcn_sqrtf(bx * bx + by * by + bz * bz);
    float lc = __builtin_amdgcn_sqrtf(cx * cx + cy * cy + cz * cz);
    float crx = by * cz - bz * cy;
    float cry = bz * cx - bx * cz;
    float crz = bx * cy - by * cx;
    float num = ax * crx + ay * cry + az * crz;
    float d01 = ax * bx + ay * by + az * bz;
    float d02 = ax * cx + ay * cy + az * cz;
    float d12 = bx * cx + by * cy + bz * cz;
    float den = la * lb * lc + d01 * lc + d02 * lb + d12 * la;
    omega += fast_atan2f(sgn * num, den);
  }

  // Dist partial: this slot's strided slice of the opposite cloud.
  float dmin = 3.402823466e38f;
#pragma unroll 2
  for (int j = slot; j < BQ; j += NSLOT) {
    float4 vj = sv[j];              // uniform -> broadcast
    float dx = vj.x - px, dy = vj.y - py, dz = vj.z - pz;
    dmin = fminf(dmin, dx * dx + dy * dy + dz * dz);
  }

  romega[wave][lane] = omega;
  rdmin[wave][lane] = dmin;
  __syncthreads();

  // Wave 0 combines the block's 8 waves in fixed order, one store per point.
  if (wave == 0 && valid) {
    float om = 0.0f;
    float dm = 3.402823466e38f;
#pragma unroll
    for (int w = 0; w < NWAVE; ++w) {
      om += romega[w][lane];
      dm = fminf(dm, rdmin[w][lane]);
    }
    int idx = (split * 16 + cloud) * BQ + q;
    omega_part[idx] = om;
    dmin_part[idx] = dm;
  }
}

// Kernel 2: per-cloud reduction. Combines the 4 splits in fixed order,
// thresholds, and tree-reduces (fixed order -> deterministic).
__global__ __launch_bounds__(1024) void reduce_kernel(
    const float* __restrict__ omega_part, const float* __restrict__ dmin_part,
    float* __restrict__ sums, unsigned int* __restrict__ flags) {
  __shared__ float rs[1024];
  __shared__ int ri[1024];
  int cloud = blockIdx.x;
  int p = threadIdx.x;

  float om = 0.0f;
  float dm = 3.402823466e38f;
  if (p < BQ) {
#pragma unroll
    for (int s = 0; s < NSPLIT; ++s) {
      int idx = (s * 16 + cloud) * BQ + p;
      om += omega_part[idx];
      dm = fminf(dm, dmin_part[idx]);
    }
  }
  float wn = om * 0.15915494309189535f;  // sum(atan2)/(2*pi)
  bool interior = (p < BQ) && (wn >= 0.99f);
  rs[p] = interior ? fmaxf(dm, 0.0f) * 10000.0f : 0.0f;
  ri[p] = interior ? 1 : 0;
  __syncthreads();
  for (int off = 512; off; off >>= 1) {
    if (p < off) {
      rs[p] += rs[p + off];
      ri[p] |= ri[p + off];
    }
    __syncthreads();
  }
  if (p == 0) {
    sums[cloud] = rs[0];
    flags[cloud] = (unsigned int)ri[0];
  }
}

__global__ void finalize_kernel(const float* __restrict__ sums,
                                const unsigned int* __restrict__ flags,
                                float* __restrict__ out) {
  if (threadIdx.x == 0) {
    float total = 0.0f;
    for (int b = 0; b < NB; ++b) {
      bool gate = (flags[b] != 0u) && (flags[NB + b] != 0u);
      if (gate) total += sums[b] + sums[NB + b];
    }
    out[0] = total * (1.0f / NB);
  }
}

extern "C" void kernel_launch(void* const* d_in, const int* in_sizes, int n_in,
                              void* d_out, int out_size, void* d_ws,
                              size_t ws_size, hipStream_t stream) {
  const float* v1 = (const float*)d_in[0];
  const float* v2 = (const float*)d_in[1];
  const int* faces = (const int*)d_in[2];
  float* out = (float*)d_out;

  // Workspace: omega_part[4][16][778], dmin_part[4][16][778], sums, flags.
  // Every entry read by kernel2 is written by kernel1 each call -> no memset.
  float* omega_part = (float*)d_ws;                       // 199168 B
  float* dmin_part = omega_part + NSPLIT * 16 * BQ;       // 199168 B
  float* sums = dmin_part + NSPLIT * 16 * BQ;             // 16 floats
  unsigned int* flags = (unsigned int*)(sums + 16);       // 16 uints

  int grid1 = 16 * PG * NSPLIT;  // 832 blocks of 512
  wn_part_kernel<<<grid1, BLOCK, 0, stream>>>(v1, v2, faces, omega_part,
                                              dmin_part);
  reduce_kernel<<<16, 1024, 0, stream>>>(omega_part, dmin_part, sums, flags);
  finalize_kernel<<<1, 64, 0, stream>>>(sums, flags, out);
}

// Round 18
// 122.334 us; speedup vs baseline: 1.2280x; 1.0026x over previous
//
#include <hip/hip_runtime.h>
#include <math.h>

// Problem constants (from reference setup_inputs)
#define BQ 778          // points per cloud
#define NF_IN 1538      // input faces
#define NF_NEW 14       // appended constant faces
#define NT 1552         // real triangles
#define NB 8            // batch
#define BLOCK 512
#define NWAVE 8         // waves per block
#define NSPLIT 4        // triangle-split blocks per (cloud, point-group)
#define NSLOT 32        // NWAVE*NSPLIT wave-slots
#define TPS 49          // triangles per slot (32*49 = 1568 >= 1552, padded)
#define TPB (NWAVE * TPS) // 392 triangles staged per block
#define PG 13           // point-groups of 64 per cloud (13*64 >= 778)

__constant__ int FACES_NEW_D[NF_NEW * 3] = {
    92, 38, 234, 234, 38, 239, 38, 122, 239, 239, 122, 279,
    122, 118, 279, 279, 118, 215, 118, 117, 215, 215, 117, 214,
    117, 119, 214, 214, 119, 121, 119, 120, 121, 121, 120, 78,
    120, 108, 78, 78, 108, 79};

// Fast atan2 (~25 VALU): validated rounds 10/12/13 (absmax 0.0).
__device__ __forceinline__ float fast_atan2f(float y, float x) {
  float ax = __builtin_fabsf(x), ay = __builtin_fabsf(y);
  float mx = fmaxf(ax, ay), mn = fminf(ax, ay);
  float r  = __builtin_amdgcn_rcpf(mx);
  float t  = mn * r;
  float e  = __builtin_fmaf(-t, mx, mn);
  t = __builtin_fmaf(e, r, t);
  float s = t * t;
  float u =                  0.00282363896258175373077393f;
  u = __builtin_fmaf(u, s, -0.0159569028764963150024414f);
  u = __builtin_fmaf(u, s,  0.0425049886107444763183594f);
  u = __builtin_fmaf(u, s, -0.0748900920152664184570312f);
  u = __builtin_fmaf(u, s,  0.106347933411598205566406f);
  u = __builtin_fmaf(u, s, -0.142027363181114196777344f);
  u = __builtin_fmaf(u, s,  0.199926957488059997558594f);
  u = __builtin_fmaf(u, s, -0.333331018686294555664062f);
  float a = __builtin_fmaf(u * s, t, t);
  a = (ay > ax) ? (1.57079632679489662f - a) : a;
  a = (x < 0.0f) ? (3.14159265358979323f - a) : a;
  return __builtin_copysignf(a, y);
}

// Transposed broadcast layout (lane = point, loop = triangles): all LDS
// reads wave-uniform -> conflict-free (confirmed R12/R13: conflicts = 0).
// R13 was latency-bound (VGPR=32: one dependent chain, ~13 eff waves/CU).
// This round: padded uniform trip count (49/slot; pad tris are (0,0,0) ->
// num=+0, den=4*la^3>0 -> atan2 contribution exactly +/-0), unroll 4 for
// 4 independent chains, launch_bounds(512,6) to keep VGPR <= ~85 so
// occupancy stays >= 24 waves/CU. Block stages only its own 392 triangles.
__global__ __launch_bounds__(BLOCK, 6) void wn_part_kernel(
    const float* __restrict__ v1, const float* __restrict__ v2,
    const int* __restrict__ faces,
    float* __restrict__ omega_part, float* __restrict__ dmin_part) {
  __shared__ float4 sv[BQ];            // 12448 B
  __shared__ ushort4 sf4[TPB];         // 3136 B (byte offsets, idx*16)
  __shared__ float romega[NWAVE][64];  // 2048 B
  __shared__ float rdmin[NWAVE][64];   // 2048 B

  int bid = blockIdx.x;
  int split = bid & (NSPLIT - 1);
  int rest = bid >> 2;
  int pg = rest % PG;
  int cloud = rest / PG;           // 0..15
  int side = cloud >> 3;
  int b = cloud & 7;

  const float* pts = (side == 0) ? (v1 + b * BQ * 3) : (v2 + b * BQ * 3);
  const float* opp = (side == 0) ? (v2 + b * BQ * 3) : (v1 + b * BQ * 3);

  int tid = threadIdx.x;
  for (int i = tid; i < BQ; i += BLOCK) {
    sv[i] = make_float4(opp[i * 3 + 0], opp[i * 3 + 1], opp[i * 3 + 2], 0.0f);
  }
  // Stage only this block's 392 triangles (global ids split*392 + f).
  for (int f = tid; f < TPB; f += BLOCK) {
    int g = split * TPB + f;
    ushort4 u = make_ushort4(0, 0, 0, 0);   // pad: degenerate (0,0,0)
    if (g < NF_IN) {
      u.x = (unsigned short)(faces[g * 3 + 0] << 4);
      u.y = (unsigned short)(faces[g * 3 + 1] << 4);
      u.z = (unsigned short)(faces[g * 3 + 2] << 4);
    } else if (g < NT) {
      int h = g - NF_IN;
      u.x = (unsigned short)(FACES_NEW_D[h * 3 + 0] << 4);
      u.y = (unsigned short)(FACES_NEW_D[h * 3 + 1] << 4);
      u.z = (unsigned short)(FACES_NEW_D[h * 3 + 2] << 4);
    }
    sf4[f] = u;
  }
  __syncthreads();

  int wave = tid >> 6;
  int lane = tid & 63;
  int q = pg * 64 + lane;
  bool valid = (q < BQ);
  int qc = valid ? q : (BQ - 1);

  const float sgn = side ? -1.0f : 1.0f;
  float px = pts[qc * 3 + 0];
  float py = pts[qc * 3 + 1];
  float pz = pts[qc * 3 + 2];

  const char* svb = (const char*)sv;

  // ---- winding partial: 49 triangles, unroll 4 for independent chains ----
  float omega = 0.0f;
  int tbase = wave * TPS;
#pragma unroll 4
  for (int k = 0; k < TPS; ++k) {
    ushort4 f = sf4[tbase + k];     // uniform -> broadcast
    float4 va = *(const float4*)(svb + f.x);
    float4 vb = *(const float4*)(svb + f.y);
    float4 vc = *(const float4*)(svb + f.z);
    float ax = va.x - px, ay = va.y - py, az = va.z - pz;
    float bx = vb.x - px, by = vb.y - py, bz = vb.z - pz;
    float cx = vc.x - px, cy = vc.y - py, cz = vc.z - pz;
    float la = __builtin_amdgcn_sqrtf(ax * ax + ay * ay + az * az);
    float lb = __builtin_amdgcn_sqrtf(bx * bx + by * by + bz * bz);
    float lc = __builtin_amdgcn_sqrtf(cx * cx + cy * cy + cz * cz);
    float crx = by * cz - bz * cy;
    float cry = bz * cx - bx * cz;
    float crz = bx * cy - by * cx;
    float num = ax * crx + ay * cry + az * crz;
    float d01 = ax * bx + ay * by + az * bz;
    float d02 = ax * cx + ay * cy + az * cz;
    float d12 = bx * cx + by * cy + bz * cz;
    float den = la * lb * lc + d01 * lc + d02 * lb + d12 * la;
    omega += fast_atan2f(sgn * num, den);
  }

  // ---- dist partial: this slot's strided slice of the opposite cloud ----
  int slot = split * NWAVE + wave;  // 0..31
  float dmin = 3.402823466e38f;
#pragma unroll 4
  for (int j = slot; j < BQ; j += NSLOT) {
    float4 vj = sv[j];              // uniform -> broadcast
    float dx = vj.x - px, dy = vj.y - py, dz = vj.z - pz;
    dmin = fminf(dmin, dx * dx + dy * dy + dz * dz);
  }

  romega[wave][lane] = omega;
  rdmin[wave][lane] = dmin;
  __syncthreads();

  // Wave 0 combines the block's 8 waves in fixed order, one store per point.
  if (wave == 0 && valid) {
    float om = 0.0f;
    float dm = 3.402823466e38f;
#pragma unroll
    for (int w = 0; w < NWAVE; ++w) {
      om += romega[w][lane];
      dm = fminf(dm, rdmin[w][lane]);
    }
    int idx = (split * 16 + cloud) * BQ + q;
    omega_part[idx] = om;
    dmin_part[idx] = dm;
  }
}

// Kernel 2: per-cloud reduction, fixed combine order -> deterministic.
__global__ __launch_bounds__(1024) void reduce_kernel(
    const float* __restrict__ omega_part, const float* __restrict__ dmin_part,
    float* __restrict__ sums, unsigned int* __restrict__ flags) {
  __shared__ float rs[1024];
  __shared__ int ri[1024];
  int cloud = blockIdx.x;
  int p = threadIdx.x;

  float om = 0.0f;
  float dm = 3.402823466e38f;
  if (p < BQ) {
#pragma unroll
    for (int s = 0; s < NSPLIT; ++s) {
      int idx = (s * 16 + cloud) * BQ + p;
      om += omega_part[idx];
      dm = fminf(dm, dmin_part[idx]);
    }
  }
  float wn = om * 0.15915494309189535f;  // sum(atan2)/(2*pi)
  bool interior = (p < BQ) && (wn >= 0.99f);
  rs[p] = interior ? fmaxf(dm, 0.0f) * 10000.0f : 0.0f;
  ri[p] = interior ? 1 : 0;
  __syncthreads();
  for (int off = 512; off; off >>= 1) {
    if (p < off) {
      rs[p] += rs[p + off];
      ri[p] |= ri[p + off];
    }
    __syncthreads();
  }
  if (p == 0) {
    sums[cloud] = rs[0];
    flags[cloud] = (unsigned int)ri[0];
  }
}

__global__ void finalize_kernel(const float* __restrict__ sums,
                                const unsigned int* __restrict__ flags,
                                float* __restrict__ out) {
  if (threadIdx.x == 0) {
    float total = 0.0f;
    for (int b = 0; b < NB; ++b) {
      bool gate = (flags[b] != 0u) && (flags[NB + b] != 0u);
      if (gate) total += sums[b] + sums[NB + b];
    }
    out[0] = total * (1.0f / NB);
  }
}

extern "C" void kernel_launch(void* const* d_in, const int* in_sizes, int n_in,
                              void* d_out, int out_size, void* d_ws,
                              size_t ws_size, hipStream_t stream) {
  const float* v1 = (const float*)d_in[0];
  const float* v2 = (const float*)d_in[1];
  const int* faces = (const int*)d_in[2];
  float* out = (float*)d_out;

  // Workspace: omega_part[4][16][778], dmin_part[4][16][778], sums, flags.
  // Every entry read by kernel2 is written by kernel1 each call -> no memset.
  float* omega_part = (float*)d_ws;                       // 199168 B
  float* dmin_part = omega_part + NSPLIT * 16 * BQ;       // 199168 B
  float* sums = dmin_part + NSPLIT * 16 * BQ;             // 16 floats
  unsigned int* flags = (unsigned int*)(sums + 16);       // 16 uints

  int grid1 = 16 * PG * NSPLIT;  // 832 blocks of 512
  wn_part_kernel<<<grid1, BLOCK, 0, stream>>>(v1, v2, faces, omega_part,
                                              dmin_part);
  reduce_kernel<<<16, 1024, 0, stream>>>(omega_part, dmin_part, sums, flags);
  finalize_kernel<<<1, 64, 0, stream>>>(sums, flags, out);
}